// Round 3
// baseline (640.050 us; speedup 1.0000x reference)
//
#include <hip/hip_runtime.h>
#include <math.h>

#define BATCH 512
#define SEQ   200
#define TOK   10
#define EMB   25
#define HID   64
#define G3    192   // 3*HID
#define XPW   384   // both directions' input projections

__device__ __forceinline__ float fast_sigmoid(float t) {
    float e = __expf(-t);
    return __builtin_amdgcn_rcpf(1.f + e);
}
__device__ __forceinline__ float fast_tanh(float t) {
    float e2 = __expf(2.f * t);
    return 1.f - 2.f * __builtin_amdgcn_rcpf(e2 + 1.f);
}

// ---------------------------------------------------------------------------
// Kernel 1: fused embedding-bag mean + input projection (both directions).
// One wave per (b,s) position, grid-stride. Lane l holds W columns
// {l, 64+l, 128+l} of W_f and of W_b in registers (150 VGPRs), so the
// 25x384 projection needs zero LDS traffic: x is broadcast via __shfl.
// Writes xp[pos][384] = [x.W_f + b_f0 | x.W_b + b_b0].
// ---------------------------------------------------------------------------
__global__ __launch_bounds__(256, 2) void emb_xproj_kernel(
    const int* __restrict__ ids_g, const float* __restrict__ emb,
    const float* __restrict__ W_f, const float* __restrict__ b_f,
    const float* __restrict__ W_b, const float* __restrict__ b_b,
    float* __restrict__ xp, float* __restrict__ mask)
{
    const int lane = threadIdx.x & 63;
    const int wave = threadIdx.x >> 6;

    // per-lane weight columns: g=0..2 -> W_f col g*64+lane, g=3..5 -> W_b
    float Wreg[EMB][6];
    float bl[6];
    #pragma unroll
    for (int g = 0; g < 3; g++) {
        #pragma unroll
        for (int e = 0; e < EMB; e++) {
            Wreg[e][g]     = W_f[e * G3 + g * 64 + lane];
            Wreg[e][g + 3] = W_b[e * G3 + g * 64 + lane];
        }
        bl[g]     = b_f[g * 64 + lane];
        bl[g + 3] = b_b[g * 64 + lane];
    }

    for (int pos = blockIdx.x * 4 + wave; pos < BATCH * SEQ; pos += gridDim.x * 4) {
        const int* ids = ids_g + (size_t)pos * TOK;
        float acc = 0.f;
        int cnt = 0;
        #pragma unroll
        for (int t = 0; t < TOK; t++) {
            int id = ids[t];
            if (id != 0) {
                cnt++;
                if (lane < EMB) acc += emb[(size_t)id * EMB + lane];
            }
        }
        float xv = cnt ? acc / (float)cnt : 0.f;
        if (lane == 0) mask[pos] = (ids[0] != 0) ? 1.f : 0.f;

        // broadcast x row to all lanes (lane e holds x[e])
        float xr[EMB];
        #pragma unroll
        for (int e = 0; e < EMB; e++) xr[e] = __shfl(xv, e);

        float* orow = xp + (size_t)pos * XPW;
        #pragma unroll
        for (int g = 0; g < 6; g++) {
            float a0 = bl[g], a1 = 0.f;
            #pragma unroll
            for (int e = 0; e < 24; e += 2) {
                a0 = fmaf(xr[e + 0], Wreg[e + 0][g], a0);
                a1 = fmaf(xr[e + 1], Wreg[e + 1][g], a1);
            }
            a0 = fmaf(xr[24], Wreg[24][g], a0);
            orow[g * 64 + lane] = a0 + a1;
        }
    }
}

// ---------------------------------------------------------------------------
// Kernel 2: GRU scan — one wave per (batch, direction), 64 threads.
// Input projections precomputed (kernel 1); lane j holds only the three
// recurrent columns Uz/Ur/Uh (192 VGPRs — fits, no AGPR spill). Per step:
// 3 coalesced xp loads (software-pipelined, distance 2), 16 ds_read_b128
// of h, 192 FMA, activations in registers, 1 ds_write broadcast. No
// barriers in the loop.
// ---------------------------------------------------------------------------
__global__ __launch_bounds__(64, 1) void gru_kernel(
    const float* __restrict__ xp, const float* __restrict__ maskg,
    const float* __restrict__ U_f, const float* __restrict__ b_f,
    const float* __restrict__ U_b, const float* __restrict__ b_b,
    float* __restrict__ outg, float* __restrict__ hT)
{
    const int bidx = blockIdx.x;
    const int dir  = bidx >> 9;        // 0 = forward, 1 = backward
    const int b    = bidx & 511;
    const int j    = threadIdx.x;      // 0..63

    const float* U    = dir ? U_b : U_f;
    const float* bias = dir ? b_b : b_f;

    float Uz[HID], Ur[HID], Uh[HID];
    #pragma unroll
    for (int k = 0; k < HID; k++) {
        Uz[k] = U[k * G3 + j];
        Ur[k] = U[k * G3 + HID + j];
        Uh[k] = U[k * G3 + 2 * HID + j];
    }
    const float bzr = bias[G3 + j];
    const float brr = bias[G3 + HID + j];
    const float bhr = bias[G3 + 2 * HID + j];

    __shared__ float ms[SEQ];
    __shared__ __align__(16) float hs[HID];

    for (int i = j; i < SEQ; i += 64) ms[i] = maskg[(size_t)b * SEQ + i];
    hs[j] = 0.f;
    __syncthreads();

    const float* xpb = xp + (size_t)b * SEQ * XPW + dir * G3 + j;
    float* orow_base = outg + (size_t)b * SEQ * (2 * HID) + dir * HID + j;
    const float4* hs4 = (const float4*)hs;

    int s = dir ? (SEQ - 1) : 0;
    const int st = dir ? -1 : 1;

    // software pipeline, distance 2
    size_t o0 = (size_t)s * XPW;
    float cz = xpb[o0], cr = xpb[o0 + 64], ch = xpb[o0 + 128];
    size_t o1 = (size_t)(s + st) * XPW;
    float nz = xpb[o1], nr = xpb[o1 + 64], nh = xpb[o1 + 128];

    float h = 0.f;
    for (int step = 0; step < SEQ; step++, s += st) {
        float tz = 0.f, tr = 0.f, th = 0.f;
        if (step + 2 < SEQ) {
            size_t o2 = (size_t)(s + 2 * st) * XPW;
            tz = xpb[o2]; tr = xpb[o2 + 64]; th = xpb[o2 + 128];
        }

        // rec_g[j] = brec_g[j] + h . U_g[:,j]
        float az0 = bzr, az1 = 0.f, ar0 = brr, ar1 = 0.f, ah0 = bhr, ah1 = 0.f;
        #pragma unroll
        for (int k4 = 0; k4 < HID / 4; k4++) {
            float4 hv = hs4[k4];
            int k = k4 * 4;
            az0 = fmaf(hv.x, Uz[k],     az0); az1 = fmaf(hv.y, Uz[k + 1], az1);
            az0 = fmaf(hv.z, Uz[k + 2], az0); az1 = fmaf(hv.w, Uz[k + 3], az1);
            ar0 = fmaf(hv.x, Ur[k],     ar0); ar1 = fmaf(hv.y, Ur[k + 1], ar1);
            ar0 = fmaf(hv.z, Ur[k + 2], ar0); ar1 = fmaf(hv.w, Ur[k + 3], ar1);
            ah0 = fmaf(hv.x, Uh[k],     ah0); ah1 = fmaf(hv.y, Uh[k + 1], ah1);
            ah0 = fmaf(hv.z, Uh[k + 2], ah0); ah1 = fmaf(hv.w, Uh[k + 3], ah1);
        }

        float z  = fast_sigmoid(cz + az0 + az1);
        float r  = fast_sigmoid(cr + ar0 + ar1);
        float hh = fast_tanh(ch + r * (ah0 + ah1));
        float hn = z * h + (1.f - z) * hh;
        hn = (ms[s] != 0.f) ? hn : h;
        h = hn;

        __builtin_amdgcn_wave_barrier();
        hs[j] = hn;
        __builtin_amdgcn_wave_barrier();

        orow_base[(size_t)s * (2 * HID)] = hn;   // fire-and-forget

        cz = nz; cr = nr; ch = nh;
        nz = tz; nr = tr; nh = th;
    }
    if (dir == 0) hT[(size_t)b * HID + j] = h;
}

// ---------------------------------------------------------------------------
// Kernel 3: attention pooling. One block (256 threads = 4 waves) per batch.
// ---------------------------------------------------------------------------
__global__ __launch_bounds__(256) void attn_kernel(
    const float* __restrict__ outg, const float* __restrict__ maskg,
    const float* __restrict__ hT,
    const float* __restrict__ W_k, const float* __restrict__ b_k,
    const float* __restrict__ W_q, const float* __restrict__ b_q,
    const float* __restrict__ W_e, const float* __restrict__ b_e,
    float* __restrict__ ctx)
{
    const int b   = blockIdx.x;
    const int tid = threadIdx.x;

    __shared__ float Wks[2 * HID * HID];   // 128x64 = 32 KB
    __shared__ float qs[HID];
    __shared__ float es[SEQ];
    __shared__ float part[2 * HID];

    for (int i = tid; i < 2 * HID * HID; i += 256) Wks[i] = W_k[i];
    if (tid < HID) {
        float q = b_q[tid];
        const float* hrow = hT + (size_t)b * HID;
        #pragma unroll 8
        for (int i = 0; i < HID; i++) q = fmaf(hrow[i], W_q[i * HID + tid], q);
        qs[tid] = q;
    }
    __syncthreads();

    const int wave = tid >> 6;
    const int lane = tid & 63;
    const float bk = b_k[lane];
    const float we = W_e[lane];
    const float be = b_e[0];

    // phase 1: scores e[s]; each wave takes every 4th s
    for (int s = wave; s < SEQ; s += 4) {
        const float4* orow4 = (const float4*)(outg + ((size_t)b * SEQ + s) * (2 * HID));
        float a0 = 0.f, a1 = 0.f, a2 = 0.f, a3 = 0.f;
        #pragma unroll
        for (int i4 = 0; i4 < (2 * HID) / 4; i4++) {
            float4 ov = orow4[i4];
            int i = i4 * 4;
            a0 = fmaf(ov.x, Wks[(i + 0) * HID + lane], a0);
            a1 = fmaf(ov.y, Wks[(i + 1) * HID + lane], a1);
            a2 = fmaf(ov.z, Wks[(i + 2) * HID + lane], a2);
            a3 = fmaf(ov.w, Wks[(i + 3) * HID + lane], a3);
        }
        float t = tanhf(((a0 + a1) + (a2 + a3)) + bk + qs[lane]) * we;
        #pragma unroll
        for (int off = 32; off > 0; off >>= 1) t += __shfl_down(t, off);
        if (lane == 0) {
            float pen = (maskg[(size_t)b * SEQ + s] != 0.f) ? 0.f : -1e9f;
            es[s] = t + be + pen;
        }
    }
    __syncthreads();

    // phase 2: softmax over the 200 scores (single wave)
    if (tid < 64) {
        float mx = -1e30f;
        for (int s2 = tid; s2 < SEQ; s2 += 64) mx = fmaxf(mx, es[s2]);
        #pragma unroll
        for (int off = 32; off > 0; off >>= 1) mx = fmaxf(mx, __shfl_xor(mx, off));
        float sum = 0.f;
        for (int s2 = tid; s2 < SEQ; s2 += 64) {
            float w = expf(es[s2] - mx);
            es[s2] = w;
            sum += w;
        }
        #pragma unroll
        for (int off = 32; off > 0; off >>= 1) sum += __shfl_xor(sum, off);
        float inv = 1.f / sum;
        for (int s2 = tid; s2 < SEQ; s2 += 64) es[s2] *= inv;
    }
    __syncthreads();

    // phase 3: context[j] = sum_s w[s] * out[b,s,j]; all 256 threads
    {
        const int half = tid >> 7;          // 0 or 1
        const int jj   = tid & 127;
        float a = 0.f;
        for (int s2 = half; s2 < SEQ; s2 += 2)
            a = fmaf(es[s2], outg[((size_t)b * SEQ + s2) * (2 * HID) + jj], a);
        if (half == 1) part[jj] = a;
        __syncthreads();
        if (half == 0)
            ctx[(size_t)b * (2 * HID) + jj] = a + part[jj];
    }
}

// ---------------------------------------------------------------------------
extern "C" void kernel_launch(void* const* d_in, const int* in_sizes, int n_in,
                              void* d_out, int out_size, void* d_ws, size_t ws_size,
                              hipStream_t stream) {
    const int*   ids = (const int*)  d_in[0];
    const float* emb = (const float*)d_in[1];
    const float* W_f = (const float*)d_in[2];
    const float* U_f = (const float*)d_in[3];
    const float* b_f = (const float*)d_in[4];
    const float* W_b = (const float*)d_in[5];
    const float* U_b = (const float*)d_in[6];
    const float* b_b = (const float*)d_in[7];
    const float* W_k = (const float*)d_in[8];
    const float* b_k = (const float*)d_in[9];
    const float* W_q = (const float*)d_in[10];
    const float* b_q = (const float*)d_in[11];
    const float* W_e = (const float*)d_in[12];
    const float* b_e = (const float*)d_in[13];

    float* ws   = (float*)d_ws;
    // workspace layout (floats):
    //   xp   : [0, 39'321'600)                (B*S*384)
    //   mask : [39'321'600, 39'424'000)       (B*S)
    //   out  : [39'424'000, 52'531'200)       (B*S*2H)
    //   hT   : [52'531'200, 52'563'968)       (B*H)
    float* xp   = ws;
    float* mask = ws + 39321600;
    float* out  = ws + 39424000;
    float* hT   = ws + 52531200;

    emb_xproj_kernel<<<1280, 256, 0, stream>>>(ids, emb, W_f, b_f, W_b, b_b,
                                               xp, mask);
    gru_kernel<<<1024, 64, 0, stream>>>(xp, mask, U_f, b_f, U_b, b_b, out, hT);
    attn_kernel<<<BATCH, 256, 0, stream>>>(out, mask, hT, W_k, b_k,
                                           W_q, b_q, W_e, b_e, (float*)d_out);
}